// Round 10
// baseline (57.369 us; speedup 1.0000x reference)
//
#include <hip/hip_runtime.h>

#define STEP 10
#define NCH  256                 // 128*2 flattened channels = DP "batches"
#define CSCL (-144.2695041f)     // -(1/GAMMA)*log2(e): scale into log2 domain
#define GLN2 (-0.00693147181f)   // -GAMMA*ln(2) == 1/CSCL (to 7e-10 rel)
#define BIGP (-1.442695041e12f)  // 1e10 * CSCL : boundary "BIG" in scaled domain
#define YOFF 64                  // pad: y idx = sb+J-i-1 >= -63
#define YLDS 384                 // YOFF + N + margin for N <= 240
#define BNDSZ 424                // absolute-diag-indexed boundary ring (no reuse)
#define NWAVE 8                  // pipeline stages (waves per batch)
#define SROW 26                  // rows per stage: 8*26 = 208 >= N = 205

// exp2/log2 via raw ISA (no fast-math dependence)
__device__ __forceinline__ float fexp2(float x){ float r; asm("v_exp_f32 %0, %1" : "=v"(r) : "v"(x)); return r; }
__device__ __forceinline__ float flog2(float x){ float r; asm("v_log_f32 %0, %1" : "=v"(r) : "v"(x)); return r; }

// Fused whole-wave shift + lane-0 boundary inject (validated R8/R9, absmax 0.0):
// lane i <- lane i-1's src, lane 0 <- old.
__device__ __forceinline__ float dpp_shr1_sel(float h, float src){
    int o = __builtin_bit_cast(int, h);
    int s = __builtin_bit_cast(int, src);
    int r = __builtin_amdgcn_update_dpp(o, s, 0x138 /*wave_shr:1*/, 0xF, 0xF, false);
    return __builtin_bit_cast(float, r);
}

// Soft-DTW cell, scaled domain R' = R*CSCL, qq precomputed off-chain.
// No boundary mask: invalid cells self-perpetuate at ~BIGP and contribute
// exactly 0.0f through exp2 in any valid cell (validated R4-R9, absmax 0.0).
__device__ __forceinline__ float dpcell(float up2, float up, float left, float qq) {
    float m  = fmaxf(fmaxf(up2, up), left);            // v_max3_f32
    float lo = fminf(fminf(up2, up), left);            // v_min3_f32
    float md = __builtin_amdgcn_fmed3f(up2, up, left); // v_med3_f32
    float e  = fexp2(lo - m) + fexp2(md - m) + 1.0f;
    float mq = m + qq;                                 // off-chain
    return flog2(e) + mq;
}

// R7's barrier-free lag pipeline, deepened to 8 stages x 26 rows so each SIMD
// hosts TWO waves of the SAME batch at ADJACENT pipeline stages (stage =
// ((w&3)<<1)|(w>>2): SIMD s gets stages 2s and 2s+1, lifetimes overlap ~82%).
// The two co-resident chains are independent -> round-robin issue hides each
// other's dpcell-chain stalls (per-step ~max(2*issue, chain) instead of
// issue+stall). Lanes >= SROW compute redundant rows: free in SIMT, never
// published (publish lane = SROW-1; result written by stage 7 only).
// Body is R7's proven distance-1 prefetch + release-after-write.
__global__ __launch_bounds__(512, 1)
void softdtw_wave(const float* __restrict__ x, const float* __restrict__ y,
                  float* __restrict__ ws, int N) {
    const int b = blockIdx.x;
    const int t = threadIdx.x;          // 0..511
    const int l = t & 63;               // lane within wave
    const int w = t >> 6;               // hardware wave 0..7
    const int stg = ((w & 3) << 1) | (w >> 2);   // pipeline stage 0..7

    __shared__ __align__(16) float Ys[YLDS];
    __shared__ float bnd[NWAVE - 1][BNDSZ];
    __shared__ int prog[NWAVE - 1];

    for (int j = t; j < YLDS; j += 512) Ys[j] = 0.f;
    float* bf = &bnd[0][0];
    for (int j = t; j < (NWAVE - 1) * BNDSZ; j += 512) bf[j] = BIGP;
    if (t < NWAVE - 1) prog[t] = 0;
    __syncthreads();
    for (int j = t; j < N; j += 512) Ys[YOFF + j] = y[j * STEP * NCH + b];
    __syncthreads();                    // startup-only block barriers

    const int off = SROW * stg;
    const int i = off + l + 1;          // my row (lanes >= SROW: redundant)
    const float xv = (i <= N) ? x[(i - 1) * STEP * NCH + b] : 0.f;

    // scaled DP state entering diag s:
    //   sp = R'(i, s-1-i)   bp = R'(i-1, s-i)   bq = R'(i-1, s-1-i)
    float sp = BIGP, bp = BIGP;
    float bq = (stg == 0 && l == 0) ? 0.0f : BIGP;  // R'[0][0] seed at s=2

    const int smax = 2 * N;
    const int sb0  = off + 2;           // first diagonal of this stage
    const int myLast = ((off + SROW < N) ? off + SROW : N) + N;   // last diag needed
    const int NG     = (myLast - sb0 + 1 + 7) >> 3;               // trimmed groups
    const bool prod = (stg < NWAVE - 1);
    const bool cons = (stg > 0);
    const int pLast = ((off < N) ? off : N) + N;    // producer's last needed diag
    const int psb0  = off - SROW + 2;
    const int pNG   = (pLast - psb0 + 1 + 7) >> 3;
    const int progFinal = psb0 + 8 * pNG - 1;       // producer's final publish

    const float* yrow = Ys + (YOFF - l);   // group m step J: yrow[8m + J]
    const float* bb = cons ? bnd[stg - 1] : bnd[0];

    #define POLL(NEED) do {                                               \
        const int need_ = min((NEED), progFinal);                         \
        while (__hip_atomic_load(&prog[stg - 1], __ATOMIC_ACQUIRE,        \
                                 __HIP_MEMORY_SCOPE_WORKGROUP) < need_)   \
            __builtin_amdgcn_s_sleep(1);                                  \
    } while (0)

    // ---- prologue: prefetch group 0 ----
    float q0,q1,q2,q3,q4,q5,q6,q7;      // qq = (xv - y)^2 * CSCL per step
    float h0,h1,h2,h3,h4,h5,h6,h7;      // boundary (row off) per step
    {
        float a0=yrow[0],a1=yrow[1],a2=yrow[2],a3=yrow[3];
        float a4=yrow[4],a5=yrow[5],a6=yrow[6],a7=yrow[7];
        if (cons) {
            POLL(sb0 + 7);
            if (l == 0) bp = bb[sb0 - 1];          // seed R'(off, 1)
            h0=bb[sb0+0]; h1=bb[sb0+1]; h2=bb[sb0+2]; h3=bb[sb0+3];
            h4=bb[sb0+4]; h5=bb[sb0+5]; h6=bb[sb0+6]; h7=bb[sb0+7];
        } else {
            h0=h1=h2=h3=h4=h5=h6=h7 = BIGP;        // row-0 wall (constant)
        }
        float d;
        d=xv-a0; q0=d*CSCL*d;  d=xv-a1; q1=d*CSCL*d;
        d=xv-a2; q2=d*CSCL*d;  d=xv-a3; q3=d*CSCL*d;
        d=xv-a4; q4=d*CSCL*d;  d=xv-a5; q5=d*CSCL*d;
        d=xv-a6; q6=d*CSCL*d;  d=xv-a7; q7=d*CSCL*d;
    }

    #define STEPJ(QQ, HJ, CJ, J) do {                              \
        CJ = dpcell(bq, bp, sp, (QQ));                             \
        float n_ = dpp_shr1_sel((HJ), CJ);                         \
        bq = bp; bp = n_; sp = CJ;                                 \
        if (sb + (J) == smax && i == N && stg == NWAVE - 1)        \
            ws[b] = CJ * GLN2;                                     \
    } while (0)

    for (int m = 0; m < NG; ++m) {
        const int sb = sb0 + 8 * m;
        float c0,c1,c2,c3,c4,c5,c6,c7;
        STEPJ(q0, h0, c0, 0); STEPJ(q1, h1, c1, 1);
        STEPJ(q2, h2, c2, 2); STEPJ(q3, h3, c3, 3);
        STEPJ(q4, h4, c4, 4); STEPJ(q5, h5, c5, 5);
        STEPJ(q6, h6, c6, 6); STEPJ(q7, h7, c7, 7);

        // batched boundary publish from the stage's last owned row (lane SROW-1)
        if (prod && l == SROW - 1) {
            float* bw = &bnd[stg][sb];
            bw[0]=c0; bw[1]=c1; bw[2]=c2; bw[3]=c3;
            bw[4]=c4; bw[5]=c5; bw[6]=c6; bw[7]=c7;
            __hip_atomic_store(&prog[stg], sb + 7, __ATOMIC_RELEASE,
                               __HIP_MEMORY_SCOPE_WORKGROUP);
        }

        // ---- prefetch group m+1 (y first — no sync dependency; then h) ----
        if (m + 1 < NG) {
            const float* yn = yrow + 8 * (m + 1);
            float a0=yn[0],a1=yn[1],a2=yn[2],a3=yn[3];
            float a4=yn[4],a5=yn[5],a6=yn[6],a7=yn[7];
            if (cons) {
                POLL(sb + 15);
                h0=bb[sb+8];  h1=bb[sb+9];  h2=bb[sb+10]; h3=bb[sb+11];
                h4=bb[sb+12]; h5=bb[sb+13]; h6=bb[sb+14]; h7=bb[sb+15];
            }
            float d;
            d=xv-a0; q0=d*CSCL*d;  d=xv-a1; q1=d*CSCL*d;
            d=xv-a2; q2=d*CSCL*d;  d=xv-a3; q3=d*CSCL*d;
            d=xv-a4; q4=d*CSCL*d;  d=xv-a5; q5=d*CSCL*d;
            d=xv-a6; q6=d*CSCL*d;  d=xv-a7; q7=d*CSCL*d;
        }
    }
    #undef STEPJ
    #undef POLL
}

// Deterministic 256 -> 1 reduction (shuffle within wave64, LDS across 4 waves)
__global__ __launch_bounds__(256)
void reduce256(const float* __restrict__ ws, float* __restrict__ out) {
    const int tid = threadIdx.x;
    float v = ws[tid];
    #pragma unroll
    for (int off = 32; off > 0; off >>= 1)
        v += __shfl_down(v, off, 64);
    __shared__ float partial[4];
    if ((tid & 63) == 0) partial[tid >> 6] = v;
    __syncthreads();
    if (tid == 0) out[0] = (partial[0] + partial[1]) + (partial[2] + partial[3]);
}

extern "C" void kernel_launch(void* const* d_in, const int* in_sizes, int n_in,
                              void* d_out, int out_size, void* d_ws, size_t ws_size,
                              hipStream_t stream) {
    const float* x = (const float*)d_in[0];
    const float* y = (const float*)d_in[1];
    float* out = (float*)d_out;
    float* ws  = (float*)d_ws;

    const int T = in_sizes[0] / NCH;            // 2048 frames
    const int L = (T + STEP - 1) / STEP;        // 205 subsampled frames

    softdtw_wave<<<dim3(NCH), dim3(512), 0, stream>>>(x, y, ws, L);
    reduce256<<<dim3(1), dim3(256), 0, stream>>>(ws, out);
}

// Round 11
// 48.233 us; speedup vs baseline: 1.1894x; 1.1894x over previous
//
#include <hip/hip_runtime.h>

#define STEP 10
#define NCH  256                 // 128*2 flattened channels = DP "batches"
#define CSCL (-144.2695041f)     // -(1/GAMMA)*log2(e): scale into log2 domain
#define GLN2 (-0.00693147181f)   // -GAMMA*ln(2) == 1/CSCL (to 7e-10 rel)
#define BIGP (-1.442695041e12f)  // 1e10 * CSCL : boundary "BIG" in scaled domain
#define YOFF 64                  // pad: y idx = sb+J-i-1 >= -63
#define YLDS 384                 // YOFF + N + margin for N <= 240
#define BNDSZ 424                // absolute-diag-indexed boundary ring (max idx 417)
#define NW   4                   // waves per batch (one per SIMD)

// exp2/log2 via raw ISA (no fast-math dependence)
__device__ __forceinline__ float fexp2(float x){ float r; asm("v_exp_f32 %0, %1" : "=v"(r) : "v"(x)); return r; }
__device__ __forceinline__ float flog2(float x){ float r; asm("v_log_f32 %0, %1" : "=v"(r) : "v"(x)); return r; }

// Fused whole-wave shift + lane-0 boundary inject (validated R8-R10, absmax 0.0)
__device__ __forceinline__ float dpp_shr1_sel(float h, float src){
    int o = __builtin_bit_cast(int, h);
    int s = __builtin_bit_cast(int, src);
    int r = __builtin_amdgcn_update_dpp(o, s, 0x138 /*wave_shr:1*/, 0xF, 0xF, false);
    return __builtin_bit_cast(float, r);
}

// Soft-DTW cell, scaled domain R' = R*CSCL, qq precomputed off-chain.
// No boundary mask: invalid cells self-perpetuate at ~BIGP and contribute
// exactly 0.0f through exp2 in any valid cell (validated R4-R10, absmax 0.0).
__device__ __forceinline__ float dpcell(float up2, float up, float left, float qq) {
    float m  = fmaxf(fmaxf(up2, up), left);            // v_max3_f32
    float lo = fminf(fminf(up2, up), left);            // v_min3_f32
    float md = __builtin_amdgcn_fmed3f(up2, up, left); // v_med3_f32
    float e  = fexp2(lo - m) + fexp2(md - m) + 1.0f;
    float mq = m + qq;                                 // off-chain
    return flog2(e) + mq;
}

// Force 8 values to be materialized in VGPRs HERE. Every pin targets loads
// issued one FULL group (~1300 cy) earlier with no younger DS ops in flight,
// so the compiler's waitcnt is instant — and the loads can no longer be sunk
// onto the DP chain (the R5/R6/R8/R10 failure mode, VGPR-minimization).
#define PIN8(A0,A1,A2,A3,A4,A5,A6,A7) \
    asm volatile("" : "+v"(A0),"+v"(A1),"+v"(A2),"+v"(A3), \
                      "+v"(A4),"+v"(A5),"+v"(A6),"+v"(A7))

// R7's barrier-free 4-wave lag pipeline (1 row/lane, 64 rows/stage, trimmed
// spans), with drain-free event placement:
//   group m (regs A) -> publish -> poll(m+2) -> PIN B (for m+1) -> issue A<-m+2
//   group m+1 (regs B) -> publish -> poll(m+3) -> PIN A (for m+2) -> issue B<-m+3
// Steps contain ZERO ds_reads (pure VALU on pinned regs). All acquire/release
// waitcnts fire when nothing recent is outstanding. Fused final reduction (R9).
__global__ __launch_bounds__(256, 1)
void softdtw_wave(const float* __restrict__ x, const float* __restrict__ y,
                  float* __restrict__ ws, int* __restrict__ cnt,
                  float* __restrict__ out, int N) {
    const int b = blockIdx.x;
    const int t = threadIdx.x;          // 0..255
    const int l = t & 63;               // lane within wave
    const int w = t >> 6;               // wave 0..3

    __shared__ __align__(16) float Ys[YLDS];
    __shared__ float bnd[NW - 1][BNDSZ];
    __shared__ int prog[NW - 1];
    __shared__ float res_s;
    __shared__ int last_s;

    for (int j = t; j < YLDS; j += 256) Ys[j] = 0.f;
    float* bf = &bnd[0][0];
    for (int j = t; j < (NW - 1) * BNDSZ; j += 256) bf[j] = BIGP;
    if (t < NW - 1) prog[t] = 0;
    __syncthreads();
    for (int j = t; j < N; j += 256) Ys[YOFF + j] = y[j * STEP * NCH + b];
    __syncthreads();                    // startup-only block barriers

    const int i = 64 * w + l + 1;       // my row
    const float xv = (i <= N) ? x[(i - 1) * STEP * NCH + b] : 0.f;

    float sp = BIGP, bp = BIGP;
    float bq = (t == 0) ? 0.0f : BIGP;  // R'[0][0] seed enters at s=2

    const int smax = 2 * N;
    const int sb0  = 64 * w + 2;
    const int myrows = (64 * (w + 1) < N) ? 64 * (w + 1) : N;
    const int NG     = (myrows + N - sb0 + 1 + 7) >> 3;   // trimmed groups
    const bool prod = (w < NW - 1);
    const bool cons = (w > 0);
    const int prows = (64 * w < N) ? 64 * w : N;
    const int pNG   = (prows + N - (sb0 - 64) + 1 + 7) >> 3;
    const int progFinal = (sb0 - 64) + 8 * pNG - 1;       // producer's last diag

    const float* yrow = Ys + (YOFF - l);   // group m step J: yrow[8m + J]
    const float* bb = cons ? bnd[w - 1] : bnd[0];

    #define POLL(NEED) do {                                               \
        const int need_ = min((NEED), progFinal);                         \
        while (__hip_atomic_load(&prog[w - 1], __ATOMIC_ACQUIRE,          \
                                 __HIP_MEMORY_SCOPE_WORKGROUP) < need_)   \
            __builtin_amdgcn_s_sleep(1);                                  \
    } while (0)

    // register double-buffer: A = even groups, B = odd groups
    float yA0,yA1,yA2,yA3,yA4,yA5,yA6,yA7, hA0,hA1,hA2,hA3,hA4,hA5,hA6,hA7;
    float yB0,yB1,yB2,yB3,yB4,yB5,yB6,yB7, hB0,hB1,hB2,hB3,hB4,hB5,hB6,hB7;

    // ---- prologue: fill A (group 0) and B (group 1) ----
    yA0=yrow[0]; yA1=yrow[1]; yA2=yrow[2]; yA3=yrow[3];
    yA4=yrow[4]; yA5=yrow[5]; yA6=yrow[6]; yA7=yrow[7];
    if (cons) {
        POLL(sb0 + 15);
        if (l == 0) bp = bb[sb0 - 1];   // seed R'(64w, 1)
        hA0=bb[sb0+0]; hA1=bb[sb0+1]; hA2=bb[sb0+2]; hA3=bb[sb0+3];
        hA4=bb[sb0+4]; hA5=bb[sb0+5]; hA6=bb[sb0+6]; hA7=bb[sb0+7];
        hB0=bb[sb0+8]; hB1=bb[sb0+9]; hB2=bb[sb0+10]; hB3=bb[sb0+11];
        hB4=bb[sb0+12]; hB5=bb[sb0+13]; hB6=bb[sb0+14]; hB7=bb[sb0+15];
    } else {
        hA0=hA1=hA2=hA3=hA4=hA5=hA6=hA7 = BIGP;   // row-0 wall
        hB0=hB1=hB2=hB3=hB4=hB5=hB6=hB7 = BIGP;
    }
    yB0=yrow[8];  yB1=yrow[9];  yB2=yrow[10]; yB3=yrow[11];
    yB4=yrow[12]; yB5=yrow[13]; yB6=yrow[14]; yB7=yrow[15];
    PIN8(yA0,yA1,yA2,yA3,yA4,yA5,yA6,yA7);   // one-time ~120cy wait, then clean
    PIN8(hA0,hA1,hA2,hA3,hA4,hA5,hA6,hA7);

    #define STEPJ(YV, HJ, CJ, J) do {                              \
        float d_ = xv - (YV);                                      \
        float q_ = d_ * CSCL * d_;                                 \
        CJ = dpcell(bq, bp, sp, q_);                               \
        float n_ = dpp_shr1_sel((HJ), CJ);                         \
        bq = bp; bp = n_; sp = CJ;                                 \
        if (sb + (J) == smax && i == N) res_s = CJ * GLN2;         \
    } while (0)

    #define PUBLISH(SB, C0,C1,C2,C3,C4,C5,C6,C7) do {              \
        if (prod && l == 63) {                                     \
            float* bw = &bnd[w][SB];                               \
            bw[0]=C0; bw[1]=C1; bw[2]=C2; bw[3]=C3;                \
            bw[4]=C4; bw[5]=C5; bw[6]=C6; bw[7]=C7;                \
            __hip_atomic_store(&prog[w], (SB) + 7, __ATOMIC_RELEASE, \
                               __HIP_MEMORY_SCOPE_WORKGROUP);      \
        }                                                          \
    } while (0)

    int m = 0;
    for (; m + 1 < NG; m += 2) {
        {   // ---- group m on A ----
            const int sb = sb0 + 8 * m;
            float c0,c1,c2,c3,c4,c5,c6,c7;
            STEPJ(yA0,hA0,c0,0); STEPJ(yA1,hA1,c1,1);
            STEPJ(yA2,hA2,c2,2); STEPJ(yA3,hA3,c3,3);
            STEPJ(yA4,hA4,c4,4); STEPJ(yA5,hA5,c5,5);
            STEPJ(yA6,hA6,c6,6); STEPJ(yA7,hA7,c7,7);
            PUBLISH(sb, c0,c1,c2,c3,c4,c5,c6,c7);
            const bool pf = (m + 2 < NG);
            if (pf && cons) POLL(sb0 + 8*(m+2) + 7);   // acquire: nothing recent in flight
            PIN8(yB0,yB1,yB2,yB3,yB4,yB5,yB6,yB7);     // B loaded one group ago -> instant
            PIN8(hB0,hB1,hB2,hB3,hB4,hB5,hB6,hB7);
            if (pf) {
                const float* yn = yrow + 8*(m+2);
                yA0=yn[0]; yA1=yn[1]; yA2=yn[2]; yA3=yn[3];
                yA4=yn[4]; yA5=yn[5]; yA6=yn[6]; yA7=yn[7];
                if (cons) {
                    const float* hh = &bb[sb0 + 8*(m+2)];
                    hA0=hh[0]; hA1=hh[1]; hA2=hh[2]; hA3=hh[3];
                    hA4=hh[4]; hA5=hh[5]; hA6=hh[6]; hA7=hh[7];
                }
                __builtin_amdgcn_sched_barrier(0);     // lock load placement here
            }
        }
        {   // ---- group m+1 on B ----
            const int sb = sb0 + 8 * (m + 1);
            float c0,c1,c2,c3,c4,c5,c6,c7;
            STEPJ(yB0,hB0,c0,0); STEPJ(yB1,hB1,c1,1);
            STEPJ(yB2,hB2,c2,2); STEPJ(yB3,hB3,c3,3);
            STEPJ(yB4,hB4,c4,4); STEPJ(yB5,hB5,c5,5);
            STEPJ(yB6,hB6,c6,6); STEPJ(yB7,hB7,c7,7);
            PUBLISH(sb, c0,c1,c2,c3,c4,c5,c6,c7);
            const bool pf = (m + 3 < NG);
            if (pf && cons) POLL(sb0 + 8*(m+3) + 7);
            PIN8(yA0,yA1,yA2,yA3,yA4,yA5,yA6,yA7);     // A(m+2) loaded one group ago
            PIN8(hA0,hA1,hA2,hA3,hA4,hA5,hA6,hA7);
            if (pf) {
                const float* yn = yrow + 8*(m+3);
                yB0=yn[0]; yB1=yn[1]; yB2=yn[2]; yB3=yn[3];
                yB4=yn[4]; yB5=yn[5]; yB6=yn[6]; yB7=yn[7];
                if (cons) {
                    const float* hh = &bb[sb0 + 8*(m+3)];
                    hB0=hh[0]; hB1=hh[1]; hB2=hh[2]; hB3=hh[3];
                    hB4=hh[4]; hB5=hh[5]; hB6=hh[6]; hB7=hh[7];
                }
                __builtin_amdgcn_sched_barrier(0);
            }
        }
    }
    if (m < NG) {   // odd tail group on A (values pinned at loop bottom)
        const int sb = sb0 + 8 * m;
        float c0,c1,c2,c3,c4,c5,c6,c7;
        STEPJ(yA0,hA0,c0,0); STEPJ(yA1,hA1,c1,1);
        STEPJ(yA2,hA2,c2,2); STEPJ(yA3,hA3,c3,3);
        STEPJ(yA4,hA4,c4,4); STEPJ(yA5,hA5,c5,5);
        STEPJ(yA6,hA6,c6,6); STEPJ(yA7,hA7,c7,7);
        PUBLISH(sb, c0,c1,c2,c3,c4,c5,c6,c7);
    }
    #undef STEPJ
    #undef PUBLISH
    #undef POLL

    // ---- fused 256 -> 1 reduction: last finished block reduces ws (R9) ----
    __syncthreads();                    // res_s written (by the i==N lane)
    if (t == 0) {
        __hip_atomic_store(&ws[b], res_s, __ATOMIC_RELEASE,
                           __HIP_MEMORY_SCOPE_AGENT);
        int prev = __hip_atomic_fetch_add(cnt, 1, __ATOMIC_ACQ_REL,
                                          __HIP_MEMORY_SCOPE_AGENT);
        last_s = (prev == NCH - 1);
    }
    __syncthreads();
    if (last_s) {                       // exactly one block runs this
        float v = __hip_atomic_load(&ws[t], __ATOMIC_RELAXED,
                                    __HIP_MEMORY_SCOPE_AGENT);
        #pragma unroll
        for (int off = 32; off > 0; off >>= 1)
            v += __shfl_down(v, off, 64);
        __shared__ float partial[4];
        if ((t & 63) == 0) partial[t >> 6] = v;
        __syncthreads();
        if (t == 0) out[0] = (partial[0] + partial[1]) + (partial[2] + partial[3]);
    }
}

extern "C" void kernel_launch(void* const* d_in, const int* in_sizes, int n_in,
                              void* d_out, int out_size, void* d_ws, size_t ws_size,
                              hipStream_t stream) {
    const float* x = (const float*)d_in[0];
    const float* y = (const float*)d_in[1];
    float* out = (float*)d_out;
    float* ws  = (float*)d_ws;
    int*   cnt = (int*)(ws + NCH);

    const int T = in_sizes[0] / NCH;            // 2048 frames
    const int L = (T + STEP - 1) / STEP;        // 205 subsampled frames

    hipMemsetAsync(cnt, 0, sizeof(int), stream);
    softdtw_wave<<<dim3(NCH), dim3(256), 0, stream>>>(x, y, ws, cnt, out, L);
}

// Round 12
// 46.379 us; speedup vs baseline: 1.2370x; 1.0400x over previous
//
#include <hip/hip_runtime.h>

#define STEP 10
#define NCH  256                 // 128*2 flattened channels = DP "batches"
#define CSCL (-144.2695041f)     // -(1/GAMMA)*log2(e): scale into log2 domain
#define GLN2 (-0.00693147181f)   // -GAMMA*ln(2) == 1/CSCL
#define YOFF 64                  // pad: y idx = sb+J-i-1 >= -63
#define YLDS 384                 // YOFF + N + margin for N <= 240
#define BNDSZ 424                // absolute-diag-indexed boundary ring (max idx 417)
#define NW   4                   // waves per batch (one per SIMD)
#define EWALL (-(1 << 27))       // exponent of the "wall" value G = 0

// raw ISA helpers (all full-rate VALU except exp2/log2 which are OFF-chain here)
__device__ __forceinline__ float fexp2(float x){ float r; asm("v_exp_f32 %0, %1" : "=v"(r) : "v"(x)); return r; }
__device__ __forceinline__ float flog2(float x){ float r; asm("v_log_f32 %0, %1" : "=v"(r) : "v"(x)); return r; }
__device__ __forceinline__ float fldexp(float x, int e){ float r; asm("v_ldexp_f32 %0, %1, %2" : "=v"(r) : "v"(x), "v"(e)); return r; }
__device__ __forceinline__ float fmant(float x){ float r; asm("v_frexp_mant_f32 %0, %1" : "=v"(r) : "v"(x)); return r; }
__device__ __forceinline__ int   fexpi(float x){ int r; asm("v_frexp_exp_i32_f32 %0, %1" : "=v"(r) : "v"(x)); return r; }

// Fused whole-wave shift + lane-0 boundary inject (validated R4-R11)
__device__ __forceinline__ float dppf(float h, float s){
    int o = __builtin_bit_cast(int, h), xx = __builtin_bit_cast(int, s);
    return __builtin_bit_cast(float, __builtin_amdgcn_update_dpp(o, xx, 0x138, 0xF, 0xF, false));
}
__device__ __forceinline__ int dppi(int h, int s){
    return __builtin_amdgcn_update_dpp(h, s, 0x138, 0xF, 0xF, false);
}

// Linear-domain soft-DTW: carry G(i,j) = 2^{R'(i,j)} as (man float, exp int).
//   G(i,j) = 2^{q'} * (G(i-1,j-1) + G(i-1,j) + G(i,j-1))
// 2^{q'} = mq * 2^{eq} computed on the PREFETCH path (the only exp2).
// Alignment by ldexp is exact; underflow-to-0 == the reference's exp2(lo-m)->0
// term drop; walls are exactly G=0 (reference walls differ by <= 2^-400: nil).
// Renormalize carried state once per 8-step group (growth <= 6^8/group, fp32
// range safe even compounded across the 4-wave pipeline).
// Structure = R7's barrier-free 4-wave lag pipeline, verbatim.
__global__ __launch_bounds__(256, 1)
void softdtw_wave(const float* __restrict__ x, const float* __restrict__ y,
                  float* __restrict__ ws, int N) {
    const int b = blockIdx.x;
    const int t = threadIdx.x;          // 0..255
    const int l = t & 63;               // lane within wave
    const int w = t >> 6;               // wave 0..3

    __shared__ __align__(16) float Ys[YLDS];
    __shared__ float bndM[NW - 1][BNDSZ];
    __shared__ int   bndE[NW - 1][BNDSZ];
    __shared__ int prog[NW - 1];

    for (int j = t; j < YLDS; j += 256) Ys[j] = 0.f;
    float* bfM = &bndM[0][0]; int* bfE = &bndE[0][0];
    for (int j = t; j < (NW - 1) * BNDSZ; j += 256) { bfM[j] = 0.f; bfE[j] = EWALL; }
    if (t < NW - 1) prog[t] = 0;
    __syncthreads();
    for (int j = t; j < N; j += 256) Ys[YOFF + j] = y[j * STEP * NCH + b];
    __syncthreads();                    // startup-only block barriers

    const int i = 64 * w + l + 1;       // my row
    const float xv = (i <= N) ? x[(i - 1) * STEP * NCH + b] : 0.f;

    // state entering diag s:  sp = G(i, s-1-i)  bp = G(i-1, s-i)  bq = G(i-1, s-1-i)
    float msp = 0.f, mbp = 0.f, mbq = (t == 0) ? 1.0f : 0.f;   // G[0][0] = 1 seed
    int   esp = EWALL, ebp = EWALL, ebq = (t == 0) ? 0 : EWALL;

    const int smax = 2 * N;
    const int sb0  = 64 * w + 2;
    const int myrows = (64 * (w + 1) < N) ? 64 * (w + 1) : N;
    const int NG     = (myrows + N - sb0 + 1 + 7) >> 3;   // trimmed groups
    const bool prod = (w < NW - 1);
    const bool cons = (w > 0);
    const int prows = (64 * w < N) ? 64 * w : N;
    const int pNG   = (prows + N - (sb0 - 64) + 1 + 7) >> 3;
    const int progFinal = (sb0 - 64) + 8 * pNG - 1;       // producer's last diag

    const float* yrow = Ys + (YOFF - l);   // group m step J: yrow[8m + J]
    const float* bbM = cons ? bndM[w - 1] : bndM[0];
    const int*   bbE = cons ? bndE[w - 1] : bndE[0];

    #define POLL(NEED) do {                                               \
        const int need_ = min((NEED), progFinal);                         \
        while (__hip_atomic_load(&prog[w - 1], __ATOMIC_ACQUIRE,          \
                                 __HIP_MEMORY_SCOPE_WORKGROUP) < need_)   \
            __builtin_amdgcn_s_sleep(1);                                  \
    } while (0)

    // per-step factor 2^{q'} = mq * 2^{eq}; exp2 lives HERE (prefetch, off-chain)
    #define QPREP(AY, MQ, EQ) do {                      \
        float d_ = xv - (AY);                           \
        float q_ = d_ * CSCL * d_;                      \
        float f_ = floorf(q_);                          \
        (EQ) = (int)f_;                                 \
        (MQ) = fexp2(q_ - f_);                          \
    } while (0)

    float mq0,mq1,mq2,mq3,mq4,mq5,mq6,mq7;  int eq0,eq1,eq2,eq3,eq4,eq5,eq6,eq7;
    float hm0,hm1,hm2,hm3,hm4,hm5,hm6,hm7;  int he0,he1,he2,he3,he4,he5,he6,he7;

    // ---- prologue: prefetch group 0 ----
    {
        float a0=yrow[0],a1=yrow[1],a2=yrow[2],a3=yrow[3];
        float a4=yrow[4],a5=yrow[5],a6=yrow[6],a7=yrow[7];
        if (cons) {
            POLL(sb0 + 7);
            if (l == 0) { mbp = bbM[sb0 - 1]; ebp = bbE[sb0 - 1]; }  // seed G(64w, 1)
            hm0=bbM[sb0+0]; hm1=bbM[sb0+1]; hm2=bbM[sb0+2]; hm3=bbM[sb0+3];
            hm4=bbM[sb0+4]; hm5=bbM[sb0+5]; hm6=bbM[sb0+6]; hm7=bbM[sb0+7];
            he0=bbE[sb0+0]; he1=bbE[sb0+1]; he2=bbE[sb0+2]; he3=bbE[sb0+3];
            he4=bbE[sb0+4]; he5=bbE[sb0+5]; he6=bbE[sb0+6]; he7=bbE[sb0+7];
        } else {
            hm0=hm1=hm2=hm3=hm4=hm5=hm6=hm7 = 0.f;      // row-0 wall: G = 0
            he0=he1=he2=he3=he4=he5=he6=he7 = EWALL;
        }
        QPREP(a0,mq0,eq0); QPREP(a1,mq1,eq1); QPREP(a2,mq2,eq2); QPREP(a3,mq3,eq3);
        QPREP(a4,mq4,eq4); QPREP(a5,mq5,eq5); QPREP(a6,mq6,eq6); QPREP(a7,mq7,eq7);
    }

    #define STEPJ(MQ, EQ, HM, HE, CM, CE, J) do {                        \
        int e1_ = ebq > ebp ? ebq : ebp; e1_ = e1_ > esp ? e1_ : esp;    \
        float a_ = fldexp(mbq, ebq - e1_);                               \
        float b_ = fldexp(mbp, ebp - e1_);                               \
        float c_ = fldexp(msp, esp - e1_);                               \
        CM = ((a_ + b_) + c_) * (MQ);                                    \
        CE = e1_ + (EQ);                                                 \
        float nm_ = dppf((HM), CM);                                      \
        int   ne_ = dppi((HE), CE);                                      \
        mbq = mbp; ebq = ebp; mbp = nm_; ebp = ne_;                      \
        msp = CM;  esp = CE;                                             \
        if (sb + (J) == smax && i == N)                                  \
            ws[b] = GLN2 * ((float)CE + flog2(CM));                      \
    } while (0)

    for (int m = 0; m < NG; ++m) {
        const int sb = sb0 + 8 * m;
        float c0,c1,c2,c3,c4,c5,c6,c7;  int g0,g1,g2,g3,g4,g5,g6,g7;
        STEPJ(mq0,eq0,hm0,he0,c0,g0,0); STEPJ(mq1,eq1,hm1,he1,c1,g1,1);
        STEPJ(mq2,eq2,hm2,he2,c2,g2,2); STEPJ(mq3,eq3,hm3,he3,c3,g3,3);
        STEPJ(mq4,eq4,hm4,he4,c4,g4,4); STEPJ(mq5,eq5,hm5,he5,c5,g5,5);
        STEPJ(mq6,eq6,hm6,he6,c6,g6,6); STEPJ(mq7,eq7,hm7,he7,c7,g7,7);

        // batched boundary publish (man + exp), one exec-mask toggle, release
        if (prod && l == 63) {
            float* bwM = &bndM[w][sb];  int* bwE = &bndE[w][sb];
            bwM[0]=c0; bwM[1]=c1; bwM[2]=c2; bwM[3]=c3;
            bwM[4]=c4; bwM[5]=c5; bwM[6]=c6; bwM[7]=c7;
            bwE[0]=g0; bwE[1]=g1; bwE[2]=g2; bwE[3]=g3;
            bwE[4]=g4; bwE[5]=g5; bwE[6]=g6; bwE[7]=g7;
            __hip_atomic_store(&prog[w], sb + 7, __ATOMIC_RELEASE,
                               __HIP_MEMORY_SCOPE_WORKGROUP);
        }

        // per-group renormalization of carried state (exact; overflow guard)
        { int kr = fexpi(msp); msp = fmant(msp); esp += kr; }

        // ---- prefetch group m+1 (y first — no sync dependency; then h) ----
        if (m + 1 < NG) {
            const float* yn = yrow + 8 * (m + 1);
            float a0=yn[0],a1=yn[1],a2=yn[2],a3=yn[3];
            float a4=yn[4],a5=yn[5],a6=yn[6],a7=yn[7];
            if (cons) {
                POLL(sb + 15);
                hm0=bbM[sb+8];  hm1=bbM[sb+9];  hm2=bbM[sb+10]; hm3=bbM[sb+11];
                hm4=bbM[sb+12]; hm5=bbM[sb+13]; hm6=bbM[sb+14]; hm7=bbM[sb+15];
                he0=bbE[sb+8];  he1=bbE[sb+9];  he2=bbE[sb+10]; he3=bbE[sb+11];
                he4=bbE[sb+12]; he5=bbE[sb+13]; he6=bbE[sb+14]; he7=bbE[sb+15];
            }
            QPREP(a0,mq0,eq0); QPREP(a1,mq1,eq1); QPREP(a2,mq2,eq2); QPREP(a3,mq3,eq3);
            QPREP(a4,mq4,eq4); QPREP(a5,mq5,eq5); QPREP(a6,mq6,eq6); QPREP(a7,mq7,eq7);
        }
    }
    #undef STEPJ
    #undef QPREP
    #undef POLL
}

// Deterministic 256 -> 1 reduction (shuffle within wave64, LDS across 4 waves)
__global__ __launch_bounds__(256)
void reduce256(const float* __restrict__ ws, float* __restrict__ out) {
    const int tid = threadIdx.x;
    float v = ws[tid];
    #pragma unroll
    for (int off = 32; off > 0; off >>= 1)
        v += __shfl_down(v, off, 64);
    __shared__ float partial[4];
    if ((tid & 63) == 0) partial[tid >> 6] = v;
    __syncthreads();
    if (tid == 0) out[0] = (partial[0] + partial[1]) + (partial[2] + partial[3]);
}

extern "C" void kernel_launch(void* const* d_in, const int* in_sizes, int n_in,
                              void* d_out, int out_size, void* d_ws, size_t ws_size,
                              hipStream_t stream) {
    const float* x = (const float*)d_in[0];
    const float* y = (const float*)d_in[1];
    float* out = (float*)d_out;
    float* ws  = (float*)d_ws;

    const int T = in_sizes[0] / NCH;            // 2048 frames
    const int L = (T + STEP - 1) / STEP;        // 205 subsampled frames

    softdtw_wave<<<dim3(NCH), dim3(256), 0, stream>>>(x, y, ws, L);
    reduce256<<<dim3(1), dim3(256), 0, stream>>>(ws, out);
}